// Round 1
// baseline (935.764 us; speedup 1.0000x reference)
//
#include <hip/hip_runtime.h>

#define NB 4096

typedef __attribute__((ext_vector_type(8))) short short8;
typedef __attribute__((ext_vector_type(4))) short short4v;
typedef __attribute__((ext_vector_type(4))) float float4v;

__device__ inline unsigned short f2bf(float f) {
  unsigned int u = __builtin_bit_cast(unsigned int, f);
  u += 0x7fffu + ((u >> 16) & 1u);   // round-to-nearest-even
  return (unsigned short)(u >> 16);
}

// ---------------------------------------------------------------------------
// Prep kernel: convert weights to bf16 in B-fragment-ready layouts, ONCE.
// ws layout (units: unsigned short):
//   [0     .. 16384): wq[4][32][128]   (per head: [e][d], e=out col, d=in dim)
//   [16384 .. 32768): wk[4][32][128]
//   [32768 .. 49152): wv[4][32][128]
//   [49152 .. 65536): wpT[128][128]    ([col][d])
// Total 131072 bytes in d_ws.
// ---------------------------------------------------------------------------
__global__ __launch_bounds__(256) void prep_weights(
    const float* __restrict__ Wq, const float* __restrict__ Wk,
    const float* __restrict__ Wv, const float* __restrict__ Wp,
    unsigned short* __restrict__ ws)
{
  int idx = blockIdx.x * 256 + threadIdx.x;
  if (idx < 49152) {
    int m = idx >> 14;              // 0=wq 1=wk 2=wv
    int r = idx & 16383;
    int h = r >> 12, e = (r >> 7) & 31, d = r & 127;
    const float* W = (m == 0) ? Wq : (m == 1) ? Wk : Wv;
    ws[idx] = f2bf(W[h * 4096 + d * 32 + e]);      // W[h][d][e] -> ws[h][e][d]
  } else if (idx < 65536) {
    int r = idx - 49152;
    int col = r >> 7, d = r & 127;
    ws[idx] = f2bf(Wp[d * 128 + col]);             // Wp[d][col] -> wpT[col][d]
  }
}

// ---------------------------------------------------------------------------
// Main kernel. LDS (shorts), total 14592 shorts = 29184 B:
//   ks [128][40]          @ 0      K for current head, B-operand layout [s][e]
//   vt [32][136]          @ 5120   V^T for current head, [e][s]
//   Ew [8][16][40]        @ 9472   per-wave C->A transpose staging
// Weights are read directly from global (bf16, L2-resident) as B-fragments.
// Barriers: 2 per head, 0 elsewhere (vs 34/block previously).
// ---------------------------------------------------------------------------
__global__ __launch_bounds__(512, 4) void mha_kernel(
    const float* __restrict__ x, const unsigned short* __restrict__ wbf,
    const float* __restrict__ bq, const float* __restrict__ bk,
    const float* __restrict__ bv, const float* __restrict__ bp,
    float* __restrict__ out)
{
  __shared__ __align__(16) unsigned short smem[14592];
  const int tid  = threadIdx.x;
  const int b    = blockIdx.x;
  const int wv_i = tid >> 6;      // wave 0..7, owns q rows [16*wv_i, 16*wv_i+16)
  const int lane = tid & 63;
  const int quad = lane >> 4;     // 0..3
  const int n16  = lane & 15;

  unsigned short* ks = smem;                       // [128][40]
  unsigned short* vt = smem + 5120;                // [32][136]
  unsigned short* Ew = smem + 9472 + wv_i * 640;   // per-wave [16][40]

  const unsigned short* wq  = wbf;
  const unsigned short* wk  = wbf + 16384;
  const unsigned short* wvw = wbf + 32768;
  const unsigned short* wpT = wbf + 49152;

  // ---- x A-fragments straight from global (own 16 rows only) ----
  const float* xrow = x + (size_t)b * 16384 + (wv_i * 16 + n16) * 128 + quad * 8;
  short8 xfrag[4];
  #pragma unroll
  for (int kk = 0; kk < 4; ++kk) {
    float4 a = *(const float4*)(xrow + kk * 32);
    float4 c = *(const float4*)(xrow + kk * 32 + 4);
    short8 f;
    f[0] = (short)f2bf(a.x); f[1] = (short)f2bf(a.y);
    f[2] = (short)f2bf(a.z); f[3] = (short)f2bf(a.w);
    f[4] = (short)f2bf(c.x); f[5] = (short)f2bf(c.y);
    f[6] = (short)f2bf(c.z); f[7] = (short)f2bf(c.w);
    xfrag[kk] = f;
  }

  // x @ W, W read as B-fragments directly from global bf16 [e][d] slab
  auto projQKV = [&](const unsigned short* wm, float4v acc[2]) {
    #pragma unroll
    for (int nt = 0; nt < 2; ++nt) {
      acc[nt] = (float4v)(0.0f);
      #pragma unroll
      for (int kk = 0; kk < 4; ++kk) {
        short8 bfr = *(const short8*)(wm + (nt * 16 + n16) * 128 + kk * 32 + quad * 8);
        acc[nt] = __builtin_amdgcn_mfma_f32_16x16x32_bf16(xfrag[kk], bfr, acc[nt], 0, 0, 0);
      }
    }
  };

  const float LOG2E_SCALE = 0.08838834764831845f * 1.4426950408889634f; // ctx^-0.5 * log2(e)

  short8 ofrag0, ofrag1, ofrag2, ofrag3;   // per-head O A-frags (static names, rule #20)

  #pragma unroll 1
  for (int h = 0; h < 4; ++h) {
    // -- projections: global reads + MFMA only, no LDS --
    float4v kacc[2], qacc[2], vacc[2];
    projQKV(wk  + h * 4096, kacc);
    projQKV(wq  + h * 4096, qacc);
    projQKV(wvw + h * 4096, vacc);

    __syncthreads();   // previous head's ks/vt reads complete

    // K -> ks[s][e]
    #pragma unroll
    for (int nt = 0; nt < 2; ++nt) {
      float bias = bk[h * 32 + nt * 16 + n16];
      #pragma unroll
      for (int r = 0; r < 4; ++r)
        ks[(wv_i * 16 + quad * 4 + r) * 40 + nt * 16 + n16] = f2bf(kacc[nt][r] + bias);
    }
    // V^T -> vt[e][s], 4 consecutive s per lane: one packed 8B store
    #pragma unroll
    for (int nt = 0; nt < 2; ++nt) {
      float bias = bv[h * 32 + nt * 16 + n16];
      short4v p;
      #pragma unroll
      for (int r = 0; r < 4; ++r) p[r] = (short)f2bf(vacc[nt][r] + bias);
      *(short4v*)(vt + (nt * 16 + n16) * 136 + wv_i * 16 + quad * 4) = p;
    }
    // Q: C->A layout round-trip through per-wave Ew (no barrier needed)
    #pragma unroll
    for (int nt = 0; nt < 2; ++nt) {
      float bias = bq[h * 32 + nt * 16 + n16];
      #pragma unroll
      for (int r = 0; r < 4; ++r)
        Ew[(quad * 4 + r) * 40 + nt * 16 + n16] = f2bf(qacc[nt][r] + bias);
    }
    short8 qfrag = *(const short8*)(Ew + n16 * 40 + quad * 8);

    __syncthreads();   // ks + vt complete

    // ---- S = Q K^T, causal: wave w needs only tiles t <= w ----
    // All register-array indices compile-time (full unroll); dynamic indexing
    // demotes to scratch (prior session post-mortem).
    float4v s[8];
    #pragma unroll
    for (int t = 0; t < 8; ++t) {
      if (t <= wv_i) {
        short8 kfr = *(const short8*)(ks + (t * 16 + n16) * 40 + quad * 8);
        float4v acc = __builtin_amdgcn_mfma_f32_16x16x32_bf16(qfrag, kfr, (float4v)(0.0f), 0, 0, 0);
        if (t == wv_i) {               // diagonal: mask s > q  <=>  n16 > quad*4+r
          #pragma unroll
          for (int r = 0; r < 4; ++r)
            if (n16 > quad * 4 + r) acc[r] = -__builtin_inff();
        }
        s[t] = acc;
      }
    }

    // ---- softmax over row (row = quad*4+r, spread across 16 lanes) ----
    float l[4];
    #pragma unroll
    for (int r = 0; r < 4; ++r) {
      float mm = -__builtin_inff();
      #pragma unroll
      for (int t = 0; t < 8; ++t) if (t <= wv_i) mm = fmaxf(mm, s[t][r]);
      #pragma unroll
      for (int off = 8; off >= 1; off >>= 1) mm = fmaxf(mm, __shfl_xor(mm, off, 64));
      float ll = 0.0f;
      #pragma unroll
      for (int t = 0; t < 8; ++t) if (t <= wv_i) {
        float p = exp2f((s[t][r] - mm) * LOG2E_SCALE);
        s[t][r] = p; ll += p;
      }
      #pragma unroll
      for (int off = 8; off >= 1; off >>= 1) ll += __shfl_xor(ll, off, 64);
      l[r] = ll;
    }

    // ---- O = P V (chunks of 32 keys; skip fully-masked chunks) ----
    float4v oacc[2] = {(float4v)(0.0f), (float4v)(0.0f)};
    #pragma unroll
    for (int c = 0; c < 4; ++c) {
      if (2 * c <= wv_i) {
        #pragma unroll
        for (int tt = 0; tt < 2; ++tt) {
          int t = 2 * c + tt;
          #pragma unroll
          for (int r = 0; r < 4; ++r)
            Ew[(quad * 4 + r) * 40 + tt * 16 + n16] =
                (t <= wv_i) ? f2bf(s[t][r]) : (unsigned short)0;
        }
        short8 pfrag = *(const short8*)(Ew + n16 * 40 + quad * 8);
        #pragma unroll
        for (int et = 0; et < 2; ++et) {
          short8 vfr = *(const short8*)(vt + (et * 16 + n16) * 136 + c * 32 + quad * 8);
          oacc[et] = __builtin_amdgcn_mfma_f32_16x16x32_bf16(pfrag, vfr, oacc[et], 0, 0, 0);
        }
      }
    }

    // epilogue: normalize, C->A round-trip, keep this head's O frag in regs
    float inv0 = 1.0f / l[0], inv1 = 1.0f / l[1], inv2 = 1.0f / l[2], inv3 = 1.0f / l[3];
    #pragma unroll
    for (int et = 0; et < 2; ++et) {
      Ew[(quad * 4 + 0) * 40 + et * 16 + n16] = f2bf(oacc[et][0] * inv0);
      Ew[(quad * 4 + 1) * 40 + et * 16 + n16] = f2bf(oacc[et][1] * inv1);
      Ew[(quad * 4 + 2) * 40 + et * 16 + n16] = f2bf(oacc[et][2] * inv2);
      Ew[(quad * 4 + 3) * 40 + et * 16 + n16] = f2bf(oacc[et][3] * inv3);
    }
    short8 of = *(const short8*)(Ew + n16 * 40 + quad * 8);
    if (h == 0) ofrag0 = of; else if (h == 1) ofrag1 = of;
    else if (h == 2) ofrag2 = of; else ofrag3 = of;
  }

  // ---- final projection: out = O @ Wp + bp  (no LDS, no barriers) ----
  float* outb = out + (size_t)b * 16384;
  const int row0 = wv_i * 16 + quad * 4;
  #pragma unroll
  for (int half = 0; half < 2; ++half) {
    #pragma unroll
    for (int nt = 0; nt < 4; ++nt) {
      int col = half * 64 + nt * 16 + n16;
      const unsigned short* wcol = wpT + col * 128 + quad * 8;
      float4v acc = (float4v)(0.0f);
      acc = __builtin_amdgcn_mfma_f32_16x16x32_bf16(ofrag0, *(const short8*)(wcol +  0), acc, 0, 0, 0);
      acc = __builtin_amdgcn_mfma_f32_16x16x32_bf16(ofrag1, *(const short8*)(wcol + 32), acc, 0, 0, 0);
      acc = __builtin_amdgcn_mfma_f32_16x16x32_bf16(ofrag2, *(const short8*)(wcol + 64), acc, 0, 0, 0);
      acc = __builtin_amdgcn_mfma_f32_16x16x32_bf16(ofrag3, *(const short8*)(wcol + 96), acc, 0, 0, 0);
      float bias = bp[col];
      #pragma unroll
      for (int r = 0; r < 4; ++r)
        outb[(size_t)(row0 + r) * 128 + col] = acc[r] + bias;
    }
  }
}

extern "C" void kernel_launch(void* const* d_in, const int* in_sizes, int n_in,
                              void* d_out, int out_size, void* d_ws, size_t ws_size,
                              hipStream_t stream) {
  const float* x  = (const float*)d_in[0];
  const float* Wq = (const float*)d_in[1];
  const float* bq = (const float*)d_in[2];
  const float* Wk = (const float*)d_in[3];
  const float* bk = (const float*)d_in[4];
  const float* Wv = (const float*)d_in[5];
  const float* bv = (const float*)d_in[6];
  const float* Wp = (const float*)d_in[7];
  const float* bp = (const float*)d_in[8];
  unsigned short* ws = (unsigned short*)d_ws;   // needs 131072 B
  prep_weights<<<dim3(256), dim3(256), 0, stream>>>(Wq, Wk, Wv, Wp, ws);
  mha_kernel<<<dim3(NB), dim3(512), 0, stream>>>(x, ws, bq, bk, bv, bp, (float*)d_out);
}

// Round 2
// 815.087 us; speedup vs baseline: 1.1481x; 1.1481x over previous
//
#include <hip/hip_runtime.h>

#define NB 4096

typedef __attribute__((ext_vector_type(8))) short short8;
typedef __attribute__((ext_vector_type(4))) short short4v;
typedef __attribute__((ext_vector_type(4))) float float4v;

__device__ inline unsigned short f2bf(float f) {
  unsigned int u = __builtin_bit_cast(unsigned int, f);
  u += 0x7fffu + ((u >> 16) & 1u);   // round-to-nearest-even
  return (unsigned short)(u >> 16);
}

// ---------------------------------------------------------------------------
// Prep kernel: weights -> bf16, B-fragment layout, XOR-swizzled so that a
// LINEAR global_load_lds into LDS yields a bank-conflict-free ds_read_b128
// image (rule: swizzle source + swizzle read, keep the DMA dest linear).
//
// ws layout (shorts), 131072 B total:
//   [0     .. 49152): wqkv[h][m][e][dsw]  m: 0=K 1=Q 2=V ; 4096 shorts/(h,m)
//                     element (e,d) stored at dsw = d ^ ((e&15)<<3)
//   [49152 .. 65536): wp[half][c][dsw]    c in [0,64); dsw = d ^ ((c&15)<<3)
// ---------------------------------------------------------------------------
__global__ __launch_bounds__(256) void prep_weights(
    const float* __restrict__ Wq, const float* __restrict__ Wk,
    const float* __restrict__ Wv, const float* __restrict__ Wp,
    unsigned short* __restrict__ ws)
{
  int idx = blockIdx.x * 256 + threadIdx.x;   // [0, 65536)
  if (idx < 49152) {
    int bm = idx >> 12;                 // h*3 + m
    int h = bm / 3, m = bm - h * 3;
    int r = idx & 4095;
    int e = r >> 7, dsw = r & 127;
    int d = dsw ^ ((e & 15) << 3);      // XOR involution
    const float* W = (m == 0) ? Wk : (m == 1) ? Wq : Wv;
    ws[idx] = f2bf(W[h * 4096 + d * 32 + e]);     // W[h][d][e]
  } else {
    int r2 = idx - 49152;
    int half = r2 >> 13, r3 = r2 & 8191;
    int c = r3 >> 7, dsw = r3 & 127;
    int d = dsw ^ ((c & 15) << 3);
    ws[idx] = f2bf(Wp[d * 128 + half * 64 + c]);  // Wp[d][col]
  }
}

// ---------------------------------------------------------------------------
// Main kernel. LDS (shorts), 26880 shorts = 53760 B -> 3 blocks/CU:
//   wlds [3][32][128]  @ 0      staged weights for current head (24576 B)
//   ks   [128][40]     @ 12288  K, B-operand layout [s][e]
//   vt   [32][136]     @ 17408  V^T [e][s]
//   Ew   [8][16][40]   @ 21760  per-wave C->A transpose staging
// Proj phase: wp-half0 overlays wlds, wp-half1 overlays ks/vt.
// Staging for head h+1 is issued right after barrier C of head h, so its
// latency hides under S/softmax/PV; barrier A (implicit vmcnt(0)) drains it.
// ---------------------------------------------------------------------------
__global__ __launch_bounds__(512, 6) void mha_kernel(
    const float* __restrict__ x, const unsigned short* __restrict__ wbf,
    const float* __restrict__ bq, const float* __restrict__ bk,
    const float* __restrict__ bv, const float* __restrict__ bp,
    float* __restrict__ out)
{
  __shared__ __align__(16) unsigned short smem[26880];
  const int tid  = threadIdx.x;
  const int b    = blockIdx.x;
  const int wv_i = tid >> 6;      // wave 0..7, owns q rows [16*wv_i, 16*wv_i+16)
  const int lane = tid & 63;
  const int quad = lane >> 4;     // 0..3
  const int n16  = lane & 15;

  unsigned short* wlds = smem;                       // [12288]
  unsigned short* ks   = smem + 12288;               // [128][40]
  unsigned short* vt   = smem + 17408;               // [32][136]
  unsigned short* Ew   = smem + 21760 + wv_i * 640;  // per-wave [16][40]
  unsigned short* wp1  = smem + 12288;               // proj half1 (16384 B)

  // async global->LDS stage: linear, 16B/lane, wave-uniform base + lane*16
  auto stage16 = [&](const unsigned short* g, unsigned short* l, int chunks) {
    #pragma unroll
    for (int i = 0; i < chunks; ++i) {
      int off = (i * 512 + tid) * 8;   // shorts (16 B per chunk)
      __builtin_amdgcn_global_load_lds(
          (const __attribute__((address_space(1))) unsigned int*)(g + off),
          (__attribute__((address_space(3))) unsigned int*)(l + off),
          16, 0, 0);
    }
  };

  // ---- x A-fragments straight from global (own 16 rows only) ----
  const float* xrow = x + (size_t)b * 16384 + (wv_i * 16 + n16) * 128 + quad * 8;
  short8 xfrag[4];
  #pragma unroll
  for (int kk = 0; kk < 4; ++kk) {
    float4 a = *(const float4*)(xrow + kk * 32);
    float4 c = *(const float4*)(xrow + kk * 32 + 4);
    short8 f;
    f[0] = (short)f2bf(a.x); f[1] = (short)f2bf(a.y);
    f[2] = (short)f2bf(a.z); f[3] = (short)f2bf(a.w);
    f[4] = (short)f2bf(c.x); f[5] = (short)f2bf(c.y);
    f[6] = (short)f2bf(c.z); f[7] = (short)f2bf(c.w);
    xfrag[kk] = f;
  }

  // prefetch head 0 weights (drained by barrier A of h=0)
  stage16(wbf, wlds, 3);

  const int swz = n16 << 3;   // XOR swizzle for weight ds_reads (bits 3-6)

  // x @ W from swizzled LDS weight image [e][dsw]
  auto projQKV = [&](const unsigned short* wm, float4v acc[2]) {
    #pragma unroll
    for (int nt = 0; nt < 2; ++nt) {
      acc[nt] = (float4v)(0.0f);
      #pragma unroll
      for (int kk = 0; kk < 4; ++kk) {
        short8 bfr = *(const short8*)(wm + (nt * 16 + n16) * 128 + ((kk * 32 + quad * 8) ^ swz));
        acc[nt] = __builtin_amdgcn_mfma_f32_16x16x32_bf16(xfrag[kk], bfr, acc[nt], 0, 0, 0);
      }
    }
  };

  const float LOG2E_SCALE = 0.08838834764831845f * 1.4426950408889634f; // ctx^-0.5 * log2(e)

  short8 ofrag0, ofrag1, ofrag2, ofrag3;   // per-head O A-frags (static names)

  #pragma unroll 1
  for (int h = 0; h < 4; ++h) {
    __syncthreads();   // A: drains staged weights; prev head's ks/vt readers done

    float4v kacc[2], qacc[2], vacc[2];
    projQKV(wlds,        kacc);
    projQKV(wlds + 4096, qacc);
    projQKV(wlds + 8192, vacc);

    // K -> ks[s][e]
    #pragma unroll
    for (int nt = 0; nt < 2; ++nt) {
      float bias = bk[h * 32 + nt * 16 + n16];
      #pragma unroll
      for (int r = 0; r < 4; ++r)
        ks[(wv_i * 16 + quad * 4 + r) * 40 + nt * 16 + n16] = f2bf(kacc[nt][r] + bias);
    }
    // V^T -> vt[e][s], packed 8B store
    #pragma unroll
    for (int nt = 0; nt < 2; ++nt) {
      float bias = bv[h * 32 + nt * 16 + n16];
      short4v p;
      #pragma unroll
      for (int r = 0; r < 4; ++r) p[r] = (short)f2bf(vacc[nt][r] + bias);
      *(short4v*)(vt + (nt * 16 + n16) * 136 + wv_i * 16 + quad * 4) = p;
    }
    // Q: C->A layout round-trip through per-wave Ew (no barrier needed)
    #pragma unroll
    for (int nt = 0; nt < 2; ++nt) {
      float bias = bq[h * 32 + nt * 16 + n16];
      #pragma unroll
      for (int r = 0; r < 4; ++r)
        Ew[(quad * 4 + r) * 40 + nt * 16 + n16] = f2bf(qacc[nt][r] + bias);
    }
    short8 qfrag = *(const short8*)(Ew + n16 * 40 + quad * 8);

    __syncthreads();   // C: ks/vt visible; all projQKV reads of wlds complete

    // prefetch NEXT stage into wlds; latency hides under S/softmax/PV
    if (h < 3) stage16(wbf + (h + 1) * 12288, wlds, 3);
    else       stage16(wbf + 49152, wlds, 2);          // Wp half 0

    // ---- S = Q K^T, causal: wave w needs only tiles t <= w ----
    float4v s[8];
    #pragma unroll
    for (int t = 0; t < 8; ++t) {
      if (t <= wv_i) {
        short8 kfr = *(const short8*)(ks + (t * 16 + n16) * 40 + quad * 8);
        float4v acc = __builtin_amdgcn_mfma_f32_16x16x32_bf16(qfrag, kfr, (float4v)(0.0f), 0, 0, 0);
        if (t == wv_i) {               // diagonal: mask s > q  <=>  n16 > quad*4+r
          #pragma unroll
          for (int r = 0; r < 4; ++r)
            if (n16 > quad * 4 + r) acc[r] = -__builtin_inff();
        }
        s[t] = acc;
      }
    }

    // ---- softmax over row (row = quad*4+r, spread across 16 lanes) ----
    float l[4];
    #pragma unroll
    for (int r = 0; r < 4; ++r) {
      float mm = -__builtin_inff();
      #pragma unroll
      for (int t = 0; t < 8; ++t) if (t <= wv_i) mm = fmaxf(mm, s[t][r]);
      #pragma unroll
      for (int off = 8; off >= 1; off >>= 1) mm = fmaxf(mm, __shfl_xor(mm, off, 64));
      float ll = 0.0f;
      #pragma unroll
      for (int t = 0; t < 8; ++t) if (t <= wv_i) {
        float p = exp2f((s[t][r] - mm) * LOG2E_SCALE);
        s[t][r] = p; ll += p;
      }
      #pragma unroll
      for (int off = 8; off >= 1; off >>= 1) ll += __shfl_xor(ll, off, 64);
      l[r] = ll;
    }

    // ---- O = P V (chunks of 32 keys; skip fully-masked chunks) ----
    float4v oacc[2] = {(float4v)(0.0f), (float4v)(0.0f)};
    #pragma unroll
    for (int c = 0; c < 4; ++c) {
      if (2 * c <= wv_i) {
        #pragma unroll
        for (int tt = 0; tt < 2; ++tt) {
          int t = 2 * c + tt;
          #pragma unroll
          for (int r = 0; r < 4; ++r)
            Ew[(quad * 4 + r) * 40 + tt * 16 + n16] =
                (t <= wv_i) ? f2bf(s[t][r]) : (unsigned short)0;
        }
        short8 pfrag = *(const short8*)(Ew + n16 * 40 + quad * 8);
        #pragma unroll
        for (int et = 0; et < 2; ++et) {
          short8 vfr = *(const short8*)(vt + (et * 16 + n16) * 136 + c * 32 + quad * 8);
          oacc[et] = __builtin_amdgcn_mfma_f32_16x16x32_bf16(pfrag, vfr, oacc[et], 0, 0, 0);
        }
      }
    }

    // epilogue: normalize, C->A round-trip, keep this head's O frag in regs
    float inv0 = 1.0f / l[0], inv1 = 1.0f / l[1], inv2 = 1.0f / l[2], inv3 = 1.0f / l[3];
    #pragma unroll
    for (int et = 0; et < 2; ++et) {
      Ew[(quad * 4 + 0) * 40 + et * 16 + n16] = f2bf(oacc[et][0] * inv0);
      Ew[(quad * 4 + 1) * 40 + et * 16 + n16] = f2bf(oacc[et][1] * inv1);
      Ew[(quad * 4 + 2) * 40 + et * 16 + n16] = f2bf(oacc[et][2] * inv2);
      Ew[(quad * 4 + 3) * 40 + et * 16 + n16] = f2bf(oacc[et][3] * inv3);
    }
    short8 of = *(const short8*)(Ew + n16 * 40 + quad * 8);
    if (h == 0) ofrag0 = of; else if (h == 1) ofrag1 = of;
    else if (h == 2) ofrag2 = of; else ofrag3 = of;
  }

  // ---- final projection: out = O @ Wp + bp ----
  __syncthreads();                       // D: drains wp-half0; ks/vt free
  stage16(wbf + 49152 + 8192, wp1, 2);   // Wp half 1 -> ks/vt region

  float* outb = out + (size_t)b * 16384;
  const int row0 = wv_i * 16 + quad * 4;

  auto projOut = [&](const unsigned short* wph, int colbase) {
    #pragma unroll
    for (int nt = 0; nt < 4; ++nt) {
      const unsigned short* wrow = wph + (nt * 16 + n16) * 128;
      float4v acc = (float4v)(0.0f);
      acc = __builtin_amdgcn_mfma_f32_16x16x32_bf16(ofrag0, *(const short8*)(wrow + ((0   + quad * 8) ^ swz)), acc, 0, 0, 0);
      acc = __builtin_amdgcn_mfma_f32_16x16x32_bf16(ofrag1, *(const short8*)(wrow + ((32  + quad * 8) ^ swz)), acc, 0, 0, 0);
      acc = __builtin_amdgcn_mfma_f32_16x16x32_bf16(ofrag2, *(const short8*)(wrow + ((64  + quad * 8) ^ swz)), acc, 0, 0, 0);
      acc = __builtin_amdgcn_mfma_f32_16x16x32_bf16(ofrag3, *(const short8*)(wrow + ((96  + quad * 8) ^ swz)), acc, 0, 0, 0);
      int col = colbase + nt * 16 + n16;
      float bias = bp[col];
      #pragma unroll
      for (int r = 0; r < 4; ++r)
        outb[(size_t)(row0 + r) * 128 + col] = acc[r] + bias;
    }
  };

  projOut(wlds, 0);      // half 0 (staged during head 3)
  __syncthreads();       // E: drains wp-half1, visible to all waves
  projOut(wp1, 64);      // half 1
}

extern "C" void kernel_launch(void* const* d_in, const int* in_sizes, int n_in,
                              void* d_out, int out_size, void* d_ws, size_t ws_size,
                              hipStream_t stream) {
  const float* x  = (const float*)d_in[0];
  const float* Wq = (const float*)d_in[1];
  const float* bq = (const float*)d_in[2];
  const float* Wk = (const float*)d_in[3];
  const float* bk = (const float*)d_in[4];
  const float* Wv = (const float*)d_in[5];
  const float* bv = (const float*)d_in[6];
  const float* Wp = (const float*)d_in[7];
  const float* bp = (const float*)d_in[8];
  unsigned short* ws = (unsigned short*)d_ws;   // needs 131072 B
  prep_weights<<<dim3(256), dim3(256), 0, stream>>>(Wq, Wk, Wv, Wp, ws);
  mha_kernel<<<dim3(NB), dim3(512), 0, stream>>>(x, ws, bq, bk, bv, bp, (float*)d_out);
}

// Round 4
// 615.949 us; speedup vs baseline: 1.5192x; 1.3233x over previous
//
#include <hip/hip_runtime.h>

#define NB 4096

typedef __attribute__((ext_vector_type(8))) short short8;
typedef __attribute__((ext_vector_type(4))) short short4v;
typedef __attribute__((ext_vector_type(4))) float float4v;

__device__ inline unsigned short f2bf(float f) {
  unsigned int u = __builtin_bit_cast(unsigned int, f);
  u += 0x7fffu + ((u >> 16) & 1u);   // round-to-nearest-even
  return (unsigned short)(u >> 16);
}

// ---------------------------------------------------------------------------
// Prep kernel: weights -> bf16, B-fragment layout, XOR-swizzled so that a
// LINEAR global_load_lds into LDS yields a bank-conflict-free ds_read_b128
// image (rule: swizzle source + swizzle read, keep the DMA dest linear).
//
// ws layout (shorts), 131072 B total:
//   [0     .. 49152): wqkv[h][m][e][dsw]  m: 0=K 1=Q 2=V ; 4096 shorts/(h,m)
//                     element (e,d) stored at dsw = d ^ ((e&15)<<3)
//   [49152 .. 65536): wp[half][c][dsw]    c in [0,64); dsw = d ^ ((c&15)<<3)
// ---------------------------------------------------------------------------
__global__ __launch_bounds__(256) void prep_weights(
    const float* __restrict__ Wq, const float* __restrict__ Wk,
    const float* __restrict__ Wv, const float* __restrict__ Wp,
    unsigned short* __restrict__ ws)
{
  int idx = blockIdx.x * 256 + threadIdx.x;   // [0, 65536)
  if (idx < 49152) {
    int bm = idx >> 12;                 // h*3 + m
    int h = bm / 3, m = bm - h * 3;
    int r = idx & 4095;
    int e = r >> 7, dsw = r & 127;
    int d = dsw ^ ((e & 15) << 3);      // XOR involution
    const float* W = (m == 0) ? Wk : (m == 1) ? Wq : Wv;
    ws[idx] = f2bf(W[h * 4096 + d * 32 + e]);     // W[h][d][e]
  } else {
    int r2 = idx - 49152;
    int half = r2 >> 13, r3 = r2 & 8191;
    int c = r3 >> 7, dsw = r3 & 127;
    int d = dsw ^ ((c & 15) << 3);
    ws[idx] = f2bf(Wp[d * 128 + half * 64 + c]);  // Wp[d][col]
  }
}

// ---------------------------------------------------------------------------
// Main kernel. LDS (shorts), 26880 shorts = 53760 B -> 3 blocks/CU (LDS cap):
//   wlds [3][32][128]  @ 0      staged weights for current head (24576 B)
//   ks   [128][40]     @ 12288  K, B-operand layout [s][e]
//   vt   [32][136]     @ 17408  V^T [e][s]
//   Ew   [8][16][40]   @ 21760  per-wave C->A transpose staging
// Proj phase: wp-half0 overlays wlds, wp-half1 overlays ks/vt.
// Staging for head h+1 is issued right after barrier C of head h, so its
// latency hides under S/softmax/PV; barrier A (implicit vmcnt(0)) drains it.
//
// __launch_bounds__ NOTE (R2 post-mortem): (512, 6) capped the allocator at
// ~85 VGPR -> compiler spilled to 40 VGPR -> +1.6 GB of scratch HBM traffic
// (FETCH and WRITE both ~1.03 GB, symmetric = spill signature). (512, 4)
// compiles this footprint at 64 VGPR with zero spills; occupancy is then
// LDS-capped at 3 blocks/CU anyway (same waves, no spills).
// ---------------------------------------------------------------------------
__global__ __launch_bounds__(512, 4) void mha_kernel(
    const float* __restrict__ x, const unsigned short* __restrict__ wbf,
    const float* __restrict__ bq, const float* __restrict__ bk,
    const float* __restrict__ bv, const float* __restrict__ bp,
    float* __restrict__ out)
{
  __shared__ __align__(16) unsigned short smem[26880];
  const int tid  = threadIdx.x;
  const int b    = blockIdx.x;
  const int wv_i = tid >> 6;      // wave 0..7, owns q rows [16*wv_i, 16*wv_i+16)
  const int lane = tid & 63;
  const int quad = lane >> 4;     // 0..3
  const int n16  = lane & 15;

  unsigned short* wlds = smem;                       // [12288]
  unsigned short* ks   = smem + 12288;               // [128][40]
  unsigned short* vt   = smem + 17408;               // [32][136]
  unsigned short* Ew   = smem + 21760 + wv_i * 640;  // per-wave [16][40]
  unsigned short* wp1  = smem + 12288;               // proj half1 (16384 B)

  // async global->LDS stage: linear, 16B/lane, wave-uniform base + lane*16
  auto stage16 = [&](const unsigned short* g, unsigned short* l, int chunks) {
    #pragma unroll
    for (int i = 0; i < chunks; ++i) {
      int off = (i * 512 + tid) * 8;   // shorts (16 B per chunk)
      __builtin_amdgcn_global_load_lds(
          (const __attribute__((address_space(1))) unsigned int*)(g + off),
          (__attribute__((address_space(3))) unsigned int*)(l + off),
          16, 0, 0);
    }
  };

  // ---- x A-fragments straight from global (own 16 rows only) ----
  const float* xrow = x + (size_t)b * 16384 + (wv_i * 16 + n16) * 128 + quad * 8;
  short8 xfrag[4];
  #pragma unroll
  for (int kk = 0; kk < 4; ++kk) {
    float4 a = *(const float4*)(xrow + kk * 32);
    float4 c = *(const float4*)(xrow + kk * 32 + 4);
    short8 f;
    f[0] = (short)f2bf(a.x); f[1] = (short)f2bf(a.y);
    f[2] = (short)f2bf(a.z); f[3] = (short)f2bf(a.w);
    f[4] = (short)f2bf(c.x); f[5] = (short)f2bf(c.y);
    f[6] = (short)f2bf(c.z); f[7] = (short)f2bf(c.w);
    xfrag[kk] = f;
  }

  // prefetch head 0 weights (drained by barrier A of h=0)
  stage16(wbf, wlds, 3);

  const int swz = n16 << 3;   // XOR swizzle for weight ds_reads (bits 3-6)

  // x @ W from swizzled LDS weight image [e][dsw]
  auto projQKV = [&](const unsigned short* wm, float4v acc[2]) {
    #pragma unroll
    for (int nt = 0; nt < 2; ++nt) {
      acc[nt] = (float4v)(0.0f);
      #pragma unroll
      for (int kk = 0; kk < 4; ++kk) {
        short8 bfr = *(const short8*)(wm + (nt * 16 + n16) * 128 + ((kk * 32 + quad * 8) ^ swz));
        acc[nt] = __builtin_amdgcn_mfma_f32_16x16x32_bf16(xfrag[kk], bfr, acc[nt], 0, 0, 0);
      }
    }
  };

  const float LOG2E_SCALE = 0.08838834764831845f * 1.4426950408889634f; // ctx^-0.5 * log2(e)

  short8 ofrag0, ofrag1, ofrag2, ofrag3;   // per-head O A-frags (static names)

  #pragma unroll 1
  for (int h = 0; h < 4; ++h) {
    __syncthreads();   // A: drains staged weights; prev head's ks/vt readers done

    float4v kacc[2], qacc[2], vacc[2];
    projQKV(wlds,        kacc);
    projQKV(wlds + 4096, qacc);
    projQKV(wlds + 8192, vacc);

    // K -> ks[s][e]
    #pragma unroll
    for (int nt = 0; nt < 2; ++nt) {
      float bias = bk[h * 32 + nt * 16 + n16];
      #pragma unroll
      for (int r = 0; r < 4; ++r)
        ks[(wv_i * 16 + quad * 4 + r) * 40 + nt * 16 + n16] = f2bf(kacc[nt][r] + bias);
    }
    // V^T -> vt[e][s], packed 8B store
    #pragma unroll
    for (int nt = 0; nt < 2; ++nt) {
      float bias = bv[h * 32 + nt * 16 + n16];
      short4v p;
      #pragma unroll
      for (int r = 0; r < 4; ++r) p[r] = (short)f2bf(vacc[nt][r] + bias);
      *(short4v*)(vt + (nt * 16 + n16) * 136 + wv_i * 16 + quad * 4) = p;
    }
    // Q: C->A layout round-trip through per-wave Ew (no barrier needed)
    #pragma unroll
    for (int nt = 0; nt < 2; ++nt) {
      float bias = bq[h * 32 + nt * 16 + n16];
      #pragma unroll
      for (int r = 0; r < 4; ++r)
        Ew[(quad * 4 + r) * 40 + nt * 16 + n16] = f2bf(qacc[nt][r] + bias);
    }
    short8 qfrag = *(const short8*)(Ew + n16 * 40 + quad * 8);

    __syncthreads();   // C: ks/vt visible; all projQKV reads of wlds complete

    // prefetch NEXT stage into wlds; latency hides under S/softmax/PV
    if (h < 3) stage16(wbf + (h + 1) * 12288, wlds, 3);
    else       stage16(wbf + 49152, wlds, 2);          // Wp half 0

    // ---- S = Q K^T, causal: wave w needs only tiles t <= w ----
    float4v s[8];
    #pragma unroll
    for (int t = 0; t < 8; ++t) {
      if (t <= wv_i) {
        short8 kfr = *(const short8*)(ks + (t * 16 + n16) * 40 + quad * 8);
        float4v acc = __builtin_amdgcn_mfma_f32_16x16x32_bf16(qfrag, kfr, (float4v)(0.0f), 0, 0, 0);
        if (t == wv_i) {               // diagonal: mask s > q  <=>  n16 > quad*4+r
          #pragma unroll
          for (int r = 0; r < 4; ++r)
            if (n16 > quad * 4 + r) acc[r] = -__builtin_inff();
        }
        s[t] = acc;
      }
    }

    // ---- softmax over row (row = quad*4+r, spread across 16 lanes) ----
    float l[4];
    #pragma unroll
    for (int r = 0; r < 4; ++r) {
      float mm = -__builtin_inff();
      #pragma unroll
      for (int t = 0; t < 8; ++t) if (t <= wv_i) mm = fmaxf(mm, s[t][r]);
      #pragma unroll
      for (int off = 8; off >= 1; off >>= 1) mm = fmaxf(mm, __shfl_xor(mm, off, 64));
      float ll = 0.0f;
      #pragma unroll
      for (int t = 0; t < 8; ++t) if (t <= wv_i) {
        float p = exp2f((s[t][r] - mm) * LOG2E_SCALE);
        s[t][r] = p; ll += p;
      }
      #pragma unroll
      for (int off = 8; off >= 1; off >>= 1) ll += __shfl_xor(ll, off, 64);
      l[r] = ll;
    }

    // ---- O = P V (chunks of 32 keys; skip fully-masked chunks) ----
    float4v oacc[2] = {(float4v)(0.0f), (float4v)(0.0f)};
    #pragma unroll
    for (int c = 0; c < 4; ++c) {
      if (2 * c <= wv_i) {
        #pragma unroll
        for (int tt = 0; tt < 2; ++tt) {
          int t = 2 * c + tt;
          #pragma unroll
          for (int r = 0; r < 4; ++r)
            Ew[(quad * 4 + r) * 40 + tt * 16 + n16] =
                (t <= wv_i) ? f2bf(s[t][r]) : (unsigned short)0;
        }
        short8 pfrag = *(const short8*)(Ew + n16 * 40 + quad * 8);
        #pragma unroll
        for (int et = 0; et < 2; ++et) {
          short8 vfr = *(const short8*)(vt + (et * 16 + n16) * 136 + c * 32 + quad * 8);
          oacc[et] = __builtin_amdgcn_mfma_f32_16x16x32_bf16(pfrag, vfr, oacc[et], 0, 0, 0);
        }
      }
    }

    // epilogue: normalize, C->A round-trip, keep this head's O frag in regs
    float inv0 = 1.0f / l[0], inv1 = 1.0f / l[1], inv2 = 1.0f / l[2], inv3 = 1.0f / l[3];
    #pragma unroll
    for (int et = 0; et < 2; ++et) {
      Ew[(quad * 4 + 0) * 40 + et * 16 + n16] = f2bf(oacc[et][0] * inv0);
      Ew[(quad * 4 + 1) * 40 + et * 16 + n16] = f2bf(oacc[et][1] * inv1);
      Ew[(quad * 4 + 2) * 40 + et * 16 + n16] = f2bf(oacc[et][2] * inv2);
      Ew[(quad * 4 + 3) * 40 + et * 16 + n16] = f2bf(oacc[et][3] * inv3);
    }
    short8 of = *(const short8*)(Ew + n16 * 40 + quad * 8);
    if (h == 0) ofrag0 = of; else if (h == 1) ofrag1 = of;
    else if (h == 2) ofrag2 = of; else ofrag3 = of;
  }

  // ---- final projection: out = O @ Wp + bp ----
  __syncthreads();                       // D: drains wp-half0; ks/vt free
  stage16(wbf + 49152 + 8192, wp1, 2);   // Wp half 1 -> ks/vt region

  float* outb = out + (size_t)b * 16384;
  const int row0 = wv_i * 16 + quad * 4;

  auto projOut = [&](const unsigned short* wph, int colbase) {
    #pragma unroll
    for (int nt = 0; nt < 4; ++nt) {
      const unsigned short* wrow = wph + (nt * 16 + n16) * 128;
      float4v acc = (float4v)(0.0f);
      acc = __builtin_amdgcn_mfma_f32_16x16x32_bf16(ofrag0, *(const short8*)(wrow + ((0   + quad * 8) ^ swz)), acc, 0, 0, 0);
      acc = __builtin_amdgcn_mfma_f32_16x16x32_bf16(ofrag1, *(const short8*)(wrow + ((32  + quad * 8) ^ swz)), acc, 0, 0, 0);
      acc = __builtin_amdgcn_mfma_f32_16x16x32_bf16(ofrag2, *(const short8*)(wrow + ((64  + quad * 8) ^ swz)), acc, 0, 0, 0);
      acc = __builtin_amdgcn_mfma_f32_16x16x32_bf16(ofrag3, *(const short8*)(wrow + ((96  + quad * 8) ^ swz)), acc, 0, 0, 0);
      int col = colbase + nt * 16 + n16;
      float bias = bp[col];
      #pragma unroll
      for (int r = 0; r < 4; ++r)
        outb[(size_t)(row0 + r) * 128 + col] = acc[r] + bias;
    }
  };

  projOut(wlds, 0);      // half 0 (staged during head 3)
  __syncthreads();       // E: drains wp-half1, visible to all waves
  projOut(wp1, 64);      // half 1
}

extern "C" void kernel_launch(void* const* d_in, const int* in_sizes, int n_in,
                              void* d_out, int out_size, void* d_ws, size_t ws_size,
                              hipStream_t stream) {
  const float* x  = (const float*)d_in[0];
  const float* Wq = (const float*)d_in[1];
  const float* bq = (const float*)d_in[2];
  const float* Wk = (const float*)d_in[3];
  const float* bk = (const float*)d_in[4];
  const float* Wv = (const float*)d_in[5];
  const float* bv = (const float*)d_in[6];
  const float* Wp = (const float*)d_in[7];
  const float* bp = (const float*)d_in[8];
  unsigned short* ws = (unsigned short*)d_ws;   // needs 131072 B
  prep_weights<<<dim3(256), dim3(256), 0, stream>>>(Wq, Wk, Wv, Wp, ws);
  mha_kernel<<<dim3(NB), dim3(512), 0, stream>>>(x, ws, bq, bk, bv, bp, (float*)d_out);
}